// Round 7
// baseline (68.282 us; speedup 1.0000x reference)
//
#include <hip/hip_runtime.h>

#define N_IN 512
#define N_VP 12
#define BATCH 65536

#define WAVES 8                    // waves per block; wave s owns a 64-col strip
#define ROWS 64                    // rows per block (= lanes per wave)
#define CPW (N_IN / WAVES)         // 64 cols per wave
#define CHUNK 8                    // cols per staged chunk
#define NCHW (CPW / CHUNK)         // 8 chunks per wave

#define GLB_CAST(p) ((const __attribute__((address_space(1))) unsigned int*)(p))
#define LDS_CAST(p) ((__attribute__((address_space(3))) unsigned int*)(p))

// ---------------------------------------------------------------------------
// Kernel A (1 block, 512 threads, fp32): W = phi * Ginv  [512][12]
//   Ginv via Newton Y <- Y(2I - G Y), Y0 = dil*I (G ~ (1/dil) I).
//   Unchanged from R5/R6 (HW-verified, absmax 0.0039).
// ---------------------------------------------------------------------------
__global__ __launch_bounds__(512) void build_W_kernel(const float* __restrict__ w,
                                                      float* __restrict__ Wg) {
    __shared__ float sphiT[N_VP][N_IN];        // transposed: rows contiguous (24 KB)
    __shared__ float Gp[2][N_VP][N_VP];
    __shared__ float G[N_VP][N_VP], Y[N_VP][N_VP], T[N_VP][N_VP];

    const int tid = threadIdx.x;
    const float dil = w[0];
    const float tr  = w[1];

    float ph[N_VP];
    {
        const float t  = (float)tid - 0.5f * (float)(N_IN - 1);
        const float xs = dil * (t - tr);
        ph[0] = 0.7511255444649425f * expf(-0.5f * xs * xs);   // pi^-1/4
        ph[1] = 1.4142135623730951f * xs * ph[0];
#pragma unroll
        for (int k = 2; k < N_VP; ++k)
            ph[k] = sqrtf(2.0f / (float)k) * xs * ph[k - 1]
                  - sqrtf((float)(k - 1) / (float)k) * ph[k - 2];
#pragma unroll
        for (int k = 0; k < N_VP; ++k) sphiT[k][tid] = ph[k];
    }
    __syncthreads();

    if (tid < 288) {                 // G = phi^T phi : 2 threads per (i,j)
        const int p = tid >> 1;
        const int i = p / N_VP, j = p % N_VP;
        const int m0 = (tid & 1) * 256;
        const float4* __restrict__ pi = reinterpret_cast<const float4*>(&sphiT[i][m0]);
        const float4* __restrict__ pj = reinterpret_cast<const float4*>(&sphiT[j][m0]);
        float s = 0.0f;
#pragma unroll 4
        for (int q = 0; q < 64; ++q) {
            const float4 a = pi[q], b = pj[q];
            s += a.x * b.x + a.y * b.y + a.z * b.z + a.w * b.w;
        }
        Gp[tid & 1][i][j] = s;
    }
    __syncthreads();
    const int ii = (tid < 144) ? tid / N_VP : 0;
    const int jj = (tid < 144) ? tid % N_VP : 0;
    if (tid < 144) {
        G[ii][jj] = Gp[0][ii][jj] + Gp[1][ii][jj];
        Y[ii][jj] = (ii == jj) ? dil : 0.0f;
    }
    __syncthreads();

    for (int it = 0; it < 3; ++it) {
        if (tid < 144) {
            float s = 0.0f;
#pragma unroll
            for (int k = 0; k < N_VP; ++k) s += G[ii][k] * Y[k][jj];
            T[ii][jj] = s;
        }
        __syncthreads();
        float v = 0.0f;
        if (tid < 144) {
            float s = 0.0f;
#pragma unroll
            for (int k = 0; k < N_VP; ++k) s += Y[ii][k] * T[k][jj];
            v = 2.0f * Y[ii][jj] - s;
        }
        __syncthreads();
        if (tid < 144) Y[ii][jj] = v;
        __syncthreads();
    }

#pragma unroll
    for (int k = 0; k < N_VP; ++k) {          // W[n][k] = sum_j Y[k][j] phi[n][j]
        float s = 0.0f;
#pragma unroll
        for (int j2 = 0; j2 < N_VP; ++j2) s += Y[k][j2] * ph[j2];
        Wg[tid * N_VP + k] = s;
    }
}

// ---------------------------------------------------------------------------
// Kernel B: out = x @ W.  OCCUPANCY round: 32 waves/CU (100%).
//   8192 waves total: 1024 blocks x 8 waves; wave s owns 64 rows x 64 cols.
//   DMA staging (global_load_lds w=16, R6-verified): LDS linear dest,
//   XOR swizzle on per-lane global source + LDS read (rule #21).
//   CHUNK=8 cols -> 2 KB/buf, 2 bufs, 8 waves = 32 KB/block -> 4 blocks/CU.
//   __launch_bounds__(512,8) caps VGPR at 64 -> 8 waves/SIMD resident.
//   Counted vmcnt(2): 2 chunks in flight. W via wave-uniform s_loads.
// ---------------------------------------------------------------------------
__global__ __launch_bounds__(512, 8) void coeffs_kernel(const float* __restrict__ x,
                                                        const float* __restrict__ Wg,
                                                        float* __restrict__ out) {
    __shared__ float4 sb[WAVES][2][2 * ROWS];  // 8 x 2 x 128 float4 = 32 KB
    const int tid  = threadIdx.x;
    const int lane = tid & 63;
    const int s    = __builtin_amdgcn_readfirstlane(tid >> 6);
    const size_t rowbase = (size_t)blockIdx.x * ROWS;
    const float* __restrict__ xq = x + rowbase * N_IN + s * CPW;
    const float* __restrict__ wbase = Wg + s * CPW * N_VP;

    // DMA source offsets (floats) for staging instrs i=0,1:
    //   tile float4 f = i*64+lane -> row t=f>>1, LDS slot q0=f&1,
    //   global col-group qg = q0 ^ (t&1)  (swizzle within each row's 32B pair)
    int off[2];
#pragma unroll
    for (int i = 0; i < 2; ++i) {
        const int f = i * 64 + lane, t = f >> 1, q0 = f & 1;
        const int qg = q0 ^ (t & 1);
        off[i] = t * N_IN + qg * 4;
    }

#define ISSUE_CHUNK(c)                                                          \
    {                                                                           \
        float4* dst_ = &sb[s][(c) & 1][0];                                      \
        __builtin_amdgcn_global_load_lds(GLB_CAST(xq + off[0] + (c) * CHUNK),   \
                                         LDS_CAST(dst_), 16, 0, 0);             \
        __builtin_amdgcn_global_load_lds(GLB_CAST(xq + off[1] + (c) * CHUNK),   \
                                         LDS_CAST(dst_ + 64), 16, 0, 0);        \
    }

    ISSUE_CHUNK(0)
    ISSUE_CHUNK(1)

    float acc[N_VP];
#pragma unroll
    for (int k = 0; k < N_VP; ++k) acc[k] = 0.0f;

    const int qsw = lane & 1;                  // read-side swizzle for this row

#pragma unroll
    for (int c = 0; c < NCHW; ++c) {
        // chunk c resident when <= 2 loads outstanding (chunk c+1's)
        if (c < NCHW - 1) asm volatile("s_waitcnt vmcnt(2)" ::: "memory");
        else              asm volatile("s_waitcnt vmcnt(0)" ::: "memory");
        __builtin_amdgcn_sched_barrier(0);

        const float4* __restrict__ buf = &sb[s][c & 1][0];
        const float4 xv0 = buf[(lane << 1) + qsw];        // global cols 0..3
        const float4 xv1 = buf[(lane << 1) + (qsw ^ 1)];  // global cols 4..7
        __builtin_amdgcn_sched_barrier(0);
        asm volatile("s_waitcnt lgkmcnt(0)" ::: "memory"); // reads done -> buf free
        __builtin_amdgcn_sched_barrier(0);
        if (c + 2 < NCHW) ISSUE_CHUNK(c + 2)

        const float* __restrict__ wb = wbase + c * (CHUNK * N_VP);
#pragma unroll
        for (int k = 0; k < N_VP; ++k) acc[k] = fmaf(xv0.x, wb[k], acc[k]);
#pragma unroll
        for (int k = 0; k < N_VP; ++k) acc[k] = fmaf(xv0.y, wb[N_VP + k], acc[k]);
#pragma unroll
        for (int k = 0; k < N_VP; ++k) acc[k] = fmaf(xv0.z, wb[2 * N_VP + k], acc[k]);
#pragma unroll
        for (int k = 0; k < N_VP; ++k) acc[k] = fmaf(xv0.w, wb[3 * N_VP + k], acc[k]);
#pragma unroll
        for (int k = 0; k < N_VP; ++k) acc[k] = fmaf(xv1.x, wb[4 * N_VP + k], acc[k]);
#pragma unroll
        for (int k = 0; k < N_VP; ++k) acc[k] = fmaf(xv1.y, wb[5 * N_VP + k], acc[k]);
#pragma unroll
        for (int k = 0; k < N_VP; ++k) acc[k] = fmaf(xv1.z, wb[6 * N_VP + k], acc[k]);
#pragma unroll
        for (int k = 0; k < N_VP; ++k) acc[k] = fmaf(xv1.w, wb[7 * N_VP + k], acc[k]);
    }

    // ---- cross-wave reduce over the 8 col-strips (aliases staging LDS) ----
    __syncthreads();
    float4* part4 = reinterpret_cast<float4*>(&sb[0][0][0]);   // [8][64*3] float4
    part4[s * 192 + lane * 3 + 0] = make_float4(acc[0], acc[1], acc[2],  acc[3]);
    part4[s * 192 + lane * 3 + 1] = make_float4(acc[4], acc[5], acc[6],  acc[7]);
    part4[s * 192 + lane * 3 + 2] = make_float4(acc[8], acc[9], acc[10], acc[11]);
    __syncthreads();
    if (tid < 192) {
        float4 r = part4[tid];
#pragma unroll
        for (int wv = 1; wv < WAVES; ++wv) {
            const float4 v = part4[wv * 192 + tid];
            r.x += v.x; r.y += v.y; r.z += v.z; r.w += v.w;
        }
        reinterpret_cast<float4*>(out + rowbase * N_VP)[tid] = r;
    }
}

extern "C" void kernel_launch(void* const* d_in, const int* in_sizes, int n_in,
                              void* d_out, int out_size, void* d_ws, size_t ws_size,
                              hipStream_t stream) {
    const float* x  = (const float*)d_in[0];   // [65536, 512] fp32
    const float* w  = (const float*)d_in[1];   // [2] fp32
    float* out      = (float*)d_out;           // [65536, 12] fp32
    float* Wg       = (float*)d_ws;            // [512][12] fp32

    build_W_kernel<<<1, 512, 0, stream>>>(w, Wg);
    coeffs_kernel<<<BATCH / ROWS, 512, 0, stream>>>(x, Wg, out);
}

// Round 8
// 43.452 us; speedup vs baseline: 1.5714x; 1.5714x over previous
//
#include <hip/hip_runtime.h>

#define N_IN 512
#define N_VP 12
#define BATCH 65536

#define WAVES 4                    // waves per block; wave s owns a col quarter
#define ROWS 64                    // rows per block (= lanes per wave)
#define CPW (N_IN / WAVES)         // 128 cols per wave
#define CHUNK 32                   // cols per staged chunk -> 128B dense segments
#define NCHW (CPW / CHUNK)         // 4 chunks per wave

// ---------------------------------------------------------------------------
// Kernel A (1 block, 512 threads, fp32): W = phi * Ginv  [512][12]
//   Ginv via Newton Y <- Y(2I - G Y), Y0 = dil*I (G ~ (1/dil) I).
//   Unchanged since R5 (HW-verified, absmax 0.0039).
// ---------------------------------------------------------------------------
__global__ __launch_bounds__(512) void build_W_kernel(const float* __restrict__ w,
                                                      float* __restrict__ Wg) {
    __shared__ float sphiT[N_VP][N_IN];        // transposed: rows contiguous (24 KB)
    __shared__ float Gp[2][N_VP][N_VP];
    __shared__ float G[N_VP][N_VP], Y[N_VP][N_VP], T[N_VP][N_VP];

    const int tid = threadIdx.x;
    const float dil = w[0];
    const float tr  = w[1];

    float ph[N_VP];
    {
        const float t  = (float)tid - 0.5f * (float)(N_IN - 1);
        const float xs = dil * (t - tr);
        ph[0] = 0.7511255444649425f * expf(-0.5f * xs * xs);   // pi^-1/4
        ph[1] = 1.4142135623730951f * xs * ph[0];
#pragma unroll
        for (int k = 2; k < N_VP; ++k)
            ph[k] = sqrtf(2.0f / (float)k) * xs * ph[k - 1]
                  - sqrtf((float)(k - 1) / (float)k) * ph[k - 2];
#pragma unroll
        for (int k = 0; k < N_VP; ++k) sphiT[k][tid] = ph[k];
    }
    __syncthreads();

    if (tid < 288) {                 // G = phi^T phi : 2 threads per (i,j)
        const int p = tid >> 1;
        const int i = p / N_VP, j = p % N_VP;
        const int m0 = (tid & 1) * 256;
        const float4* __restrict__ pi = reinterpret_cast<const float4*>(&sphiT[i][m0]);
        const float4* __restrict__ pj = reinterpret_cast<const float4*>(&sphiT[j][m0]);
        float s = 0.0f;
#pragma unroll 4
        for (int q = 0; q < 64; ++q) {
            const float4 a = pi[q], b = pj[q];
            s += a.x * b.x + a.y * b.y + a.z * b.z + a.w * b.w;
        }
        Gp[tid & 1][i][j] = s;
    }
    __syncthreads();
    const int ii = (tid < 144) ? tid / N_VP : 0;
    const int jj = (tid < 144) ? tid % N_VP : 0;
    if (tid < 144) {
        G[ii][jj] = Gp[0][ii][jj] + Gp[1][ii][jj];
        Y[ii][jj] = (ii == jj) ? dil : 0.0f;
    }
    __syncthreads();

    for (int it = 0; it < 3; ++it) {
        if (tid < 144) {
            float s = 0.0f;
#pragma unroll
            for (int k = 0; k < N_VP; ++k) s += G[ii][k] * Y[k][jj];
            T[ii][jj] = s;
        }
        __syncthreads();
        float v = 0.0f;
        if (tid < 144) {
            float s = 0.0f;
#pragma unroll
            for (int k = 0; k < N_VP; ++k) s += Y[ii][k] * T[k][jj];
            v = 2.0f * Y[ii][jj] - s;
        }
        __syncthreads();
        if (tid < 144) Y[ii][jj] = v;
        __syncthreads();
    }

#pragma unroll
    for (int k = 0; k < N_VP; ++k) {          // W[n][k] = sum_j Y[k][j] phi[n][j]
        float s = 0.0f;
#pragma unroll
        for (int j2 = 0; j2 < N_VP; ++j2) s += Y[k][j2] * ph[j2];
        Wg[tid * N_VP + k] = s;
    }
}

// ---------------------------------------------------------------------------
// Kernel B: out = x @ W.  GRANULARITY round.
//   R5 structure (compiler-scheduled, reg-staged, 16 waves/CU) with CHUNK=32:
//   - global loads fully LINEAR per instr: 8 rows x 128B dense segments.
//   - single 8KB LDS buffer per wave (32KB/block -> 4 blocks/CU); per-wave
//     in-order DS pipe makes read(c) -> write(c+1) on one buffer safe, 0 barriers.
//   - XOR slot swizzle ON THE DS_WRITE side: slot = q0 ^ (t&7); read side
//     slot = g ^ (r&7). Both 8-lanes-per-bank-quad = conflict-free optimal.
//   - W indexed by wave-uniform g -> SGPR s_loads.
//   - 2 reg prefetch buffers (R5-verified rotation), prefetch distance 2 chunks.
// ---------------------------------------------------------------------------
__global__ __launch_bounds__(256, 4) void coeffs_kernel(const float* __restrict__ x,
                                                        const float* __restrict__ Wg,
                                                        float* __restrict__ out) {
    __shared__ float sb[WAVES][ROWS][CHUNK];   // 32 KB; wave-private 8KB slices
    const int tid  = threadIdx.x;
    const int lane = tid & 63;
    const int s    = __builtin_amdgcn_readfirstlane(tid >> 6);
    const size_t rowbase = (size_t)blockIdx.x * ROWS;
    const float* __restrict__ xq = x + rowbase * N_IN + s * CPW;
    const float* __restrict__ wbase = Wg + s * CPW * N_VP;

    // Staging geometry: instr i (i=0..7), lane -> tile float4 f = i*64+lane,
    // row t = i*8 + (lane>>3), col group q0 = lane&7 (16B each).
    const int t0 = lane >> 3, q0 = lane & 7;
    const int gbase = t0 * N_IN + q0 * 4;                  // + i*8*N_IN + c*CHUNK
    float* const wr0 = &sb[s][0][0] + t0 * CHUNK + ((q0 ^ (t0 & 7)) << 2);
    // per-instr LDS delta: +8 rows = +256 floats; (t&7) invariant under t+8.

    // Per-lane LDS read pointers for global group g (reused every chunk).
    const float* rd[8];
#pragma unroll
    for (int g = 0; g < 8; ++g)
        rd[g] = &sb[s][lane][(g ^ (lane & 7)) << 2];

#define LOADC(c, pre)                                                          \
    {                                                                          \
        _Pragma("unroll")                                                      \
        for (int i_ = 0; i_ < 8; ++i_)                                         \
            pre[i_] = *reinterpret_cast<const float4*>(                        \
                xq + gbase + i_ * 8 * N_IN + (c) * CHUNK);                     \
    }
#define STOREC(pre)                                                            \
    {                                                                          \
        _Pragma("unroll")                                                      \
        for (int i_ = 0; i_ < 8; ++i_)                                         \
            *reinterpret_cast<float4*>(wr0 + i_ * 8 * CHUNK) = pre[i_];        \
    }

    float4 preA[8], preB[8];
    LOADC(0, preA)
    STOREC(preA)
    LOADC(1, preB)

    float acc[N_VP];
#pragma unroll
    for (int k = 0; k < N_VP; ++k) acc[k] = 0.0f;

#pragma unroll
    for (int c = 0; c < NCHW; ++c) {
        // ---- compute chunk c from LDS (8 ds_read_b128 + 384 FMA) ----
        const float* __restrict__ wc = wbase + c * (CHUNK * N_VP);
#pragma unroll
        for (int g = 0; g < 8; ++g) {
            const float4 xv = *reinterpret_cast<const float4*>(rd[g]);
            const float* __restrict__ w4 = wc + g * (4 * N_VP);
#pragma unroll
            for (int k = 0; k < N_VP; ++k) acc[k] = fmaf(xv.x, w4[k], acc[k]);
#pragma unroll
            for (int k = 0; k < N_VP; ++k) acc[k] = fmaf(xv.y, w4[N_VP + k], acc[k]);
#pragma unroll
            for (int k = 0; k < N_VP; ++k) acc[k] = fmaf(xv.z, w4[2 * N_VP + k], acc[k]);
#pragma unroll
            for (int k = 0; k < N_VP; ++k) acc[k] = fmaf(xv.w, w4[3 * N_VP + k], acc[k]);
        }
        // ---- pipeline: chunk c+1 (in regs) -> LDS; chunk c+2 -> freed regs ----
        if (c + 1 < NCHW) {
            if (c & 1) { STOREC(preA) } else { STOREC(preB) }   // holds chunk c+1
        }
        if (c + 2 < NCHW) {
            if (c & 1) { LOADC(c + 2, preB) } else { LOADC(c + 2, preA) }
        }
    }

    // ---- cross-wave reduce over the 4 col-quarters (aliases staging LDS) ----
    __syncthreads();
    float4* part4 = reinterpret_cast<float4*>(&sb[0][0][0]);   // [4][64*3] float4
    part4[s * 192 + lane * 3 + 0] = make_float4(acc[0], acc[1], acc[2],  acc[3]);
    part4[s * 192 + lane * 3 + 1] = make_float4(acc[4], acc[5], acc[6],  acc[7]);
    part4[s * 192 + lane * 3 + 2] = make_float4(acc[8], acc[9], acc[10], acc[11]);
    __syncthreads();
    if (tid < 192) {
        const float4 v0 = part4[tid], v1 = part4[192 + tid];
        const float4 v2 = part4[384 + tid], v3 = part4[576 + tid];
        float4 r;
        r.x = (v0.x + v1.x) + (v2.x + v3.x);
        r.y = (v0.y + v1.y) + (v2.y + v3.y);
        r.z = (v0.z + v1.z) + (v2.z + v3.z);
        r.w = (v0.w + v1.w) + (v2.w + v3.w);
        reinterpret_cast<float4*>(out + rowbase * N_VP)[tid] = r;
    }
}

extern "C" void kernel_launch(void* const* d_in, const int* in_sizes, int n_in,
                              void* d_out, int out_size, void* d_ws, size_t ws_size,
                              hipStream_t stream) {
    const float* x  = (const float*)d_in[0];   // [65536, 512] fp32
    const float* w  = (const float*)d_in[1];   // [2] fp32
    float* out      = (float*)d_out;           // [65536, 12] fp32
    float* Wg       = (float*)d_ws;            // [512][12] fp32

    build_W_kernel<<<1, 512, 0, stream>>>(w, Wg);
    coeffs_kernel<<<BATCH / ROWS, 256, 0, stream>>>(x, Wg, out);
}